// Round 5
// baseline (115.407 us; speedup 1.0000x reference)
//
#include <hip/hip_runtime.h>
#include <hip/hip_bf16.h>

using f32x4    = __attribute__((ext_vector_type(4))) float;
using bf16x8   = __attribute__((ext_vector_type(8))) __bf16;
using ushort8  = __attribute__((ext_vector_type(8))) unsigned short;
using ushort4v = __attribute__((ext_vector_type(4))) unsigned short;
using float4v  = __attribute__((ext_vector_type(4))) float;

#define LOG2E 1.44269504088896340736f
#define SHIFT_L2 5.77078016355585f   // 4 * log2(e): p = exp(s_true - 4)

static __device__ __forceinline__ unsigned short f2bf(float f) {
  union { __hip_bfloat16 h; unsigned short u; } cv;
  cv.h = __float2bfloat16(f);
  return cv.u;
}
static __device__ __forceinline__ bf16x8 ld_bf8_g(const unsigned short* p) {
  ushort8 u = *(const ushort8*)p;
  return __builtin_bit_cast(bf16x8, u);
}
static __device__ __forceinline__ bf16x8 ld_bf8_l(const char* p) {
  ushort8 u = *(const ushort8*)p;
  return __builtin_bit_cast(bf16x8, u);
}
static __device__ __forceinline__ float fast_exp2(float x) {
#if __has_builtin(__builtin_amdgcn_exp2f)
  return __builtin_amdgcn_exp2f(x);
#else
  return exp2f(x);
#endif
}

// ---------------- W prep: Wt[col(0..191)][k(0..1023)] bf16 -------------------
__global__ __launch_bounds__(256) void wprep_kernel(
    const float* __restrict__ wq, const float* __restrict__ wk,
    const float* __restrict__ wv, unsigned short* __restrict__ Wt) {
  int idx = blockIdx.x * 256 + threadIdx.x;   // 0 .. 196607
  int col = idx >> 10;                        // 0..191
  int k   = idx & 1023;
  const float* w = (col < 64) ? wq : (col < 128) ? wk : wv;
  int c = col & 63;
  Wt[idx] = f2bf(w[k * 64 + c]);
}

// -------- QKV projection: BM=32 (512 blocks, 2/CU), BN=192, BK=64 -----------
// q scaled by 1/8*log2(e) (folds softmax scale + exp2 conversion); k plain;
// v TRANSPOSED as vt[b][64][4096]
__global__ __launch_bounds__(256) void proj_kernel(
    const float* __restrict__ x, const unsigned short* __restrict__ Wt,
    const float* __restrict__ bq, const float* __restrict__ bk,
    const float* __restrict__ bv,
    unsigned short* __restrict__ qb, unsigned short* __restrict__ kb,
    unsigned short* __restrict__ vt) {
  __shared__ __align__(16) char As[32 * 128];   // [32 rows][64 k] bf16, swz (row&7)<<4
  __shared__ __align__(16) char Bs[192 * 128];  // [192 col][64 k] bf16, swz (col&7)<<4
  int tid = threadIdx.x, wave = tid >> 6, lane = tid & 63;
  int rowBase = blockIdx.x * 32;
  int rhalf = (wave & 1) * 16;     // 16-row half
  int chalf = (wave >> 1) * 96;    // 96-col half
  int l15 = lane & 15, lh = lane >> 4;

  f32x4 zero4 = {0.f, 0.f, 0.f, 0.f};
  f32x4 acc[6];
#pragma unroll
  for (int i = 0; i < 6; ++i) acc[i] = zero4;

  for (int kt = 0; kt < 16; ++kt) {
    int k0 = kt * 64;
    {  // stage A: x fp32 -> bf16
      int row = tid >> 3, c0 = (tid & 7) * 8;
      const float4v* src = (const float4v*)(x + (size_t)(rowBase + row) * 1024 + k0 + c0);
      float4v f0 = src[0], f1 = src[1];
      ushort8 u;
#pragma unroll
      for (int e = 0; e < 4; ++e) { u[e] = f2bf(f0[e]); u[4 + e] = f2bf(f1[e]); }
      *(ushort8*)(As + ((row * 128 + c0 * 2) ^ ((row & 7) << 4))) = u;
    }
#pragma unroll
    for (int i = 0; i < 6; ++i) {  // stage B: Wt bf16 [192 col][64 k]
      int c = tid + 256 * i;
      int col = c >> 3, kc = c & 7;
      ushort8 v = *(const ushort8*)(Wt + (size_t)col * 1024 + k0 + kc * 8);
      *(ushort8*)(Bs + ((col * 128 + kc * 16) ^ ((col & 7) << 4))) = v;
    }
    __syncthreads();
    bf16x8 a[2];
#pragma unroll
    for (int ks = 0; ks < 2; ++ks) {
      int row = rhalf + l15;
      a[ks] = ld_bf8_l(As + ((row * 128 + ks * 64 + lh * 16) ^ ((row & 7) << 4)));
    }
#pragma unroll
    for (int cf = 0; cf < 6; ++cf) {
      int col = chalf + cf * 16 + l15;
#pragma unroll
      for (int ks = 0; ks < 2; ++ks) {
        bf16x8 b = ld_bf8_l(Bs + ((col * 128 + ks * 64 + lh * 16) ^ ((col & 7) << 4)));
        acc[cf] = __builtin_amdgcn_mfma_f32_16x16x32_bf16(a[ks], b, acc[cf], 0, 0, 0);
      }
    }
    __syncthreads();
  }
  int b = rowBase >> 12;
  int sLoc = rowBase & 4095;
#pragma unroll
  for (int cf = 0; cf < 6; ++cf) {
    int col = chalf + cf * 16 + l15;
    int sel = col >> 6, c64 = col & 63;
    const float* bias = (sel == 0) ? bq : (sel == 1) ? bk : bv;
    float bb = bias[c64];
    if (sel < 2) {
      unsigned short* dst = (sel == 0) ? qb : kb;
      float scale = (sel == 0) ? (0.125f * LOG2E) : 1.0f;
#pragma unroll
      for (int r = 0; r < 4; ++r) {
        int row = rowBase + rhalf + lh * 4 + r;
        dst[(size_t)row * 64 + c64] = f2bf((acc[cf][r] + bb) * scale);
      }
    } else {
      ushort4v w;
#pragma unroll
      for (int r = 0; r < 4; ++r) w[r] = f2bf(acc[cf][r] + bb);
      int s0 = sLoc + rhalf + lh * 4;
      *(ushort4v*)(vt + (size_t)b * 262144 + (size_t)c64 * 4096 + s0) = w;
    }
  }
}

// ---- causal flash attention, fixed-shift softmax, K prefetch pipeline ------
// 512 blocks x 8 waves. Block = one 32-row Q tile; waves split KV steps 8-way.
__global__ __launch_bounds__(512, 4) void attn_kernel(
    const unsigned short* __restrict__ qb, const unsigned short* __restrict__ kb,
    const unsigned short* __restrict__ vt, float* __restrict__ out) {
  __shared__ __align__(16) char Pb[8][2048];   // per-wave P [32q][32kv] bf16, swz (row&3)<<4
  __shared__ __align__(16) float obuf[2048];   // merge O [32][64] f32
  __shared__ float lsumb[32];

  int tid = threadIdx.x, wave = tid >> 6, lane = tid & 63;
  int l15 = lane & 15, lh = lane >> 4;
  int bid = blockIdx.x;
  int batch = bid & 3;                 // batch == bid%4, XCD == bid%8 -> 1 batch/XCD
  int j = bid >> 2;
  int t = (j < 64) ? (127 - j) : (j - 64);   // pair t with 127-t per CU
  int qbase = t * 32;
  const size_t bO = (size_t)batch * 262144;

  for (int i = tid; i < 2048; i += 512) obuf[i] = 0.f;
  if (tid < 32) lsumb[tid] = 0.f;

  bf16x8 qf[2][2];
#pragma unroll
  for (int rf = 0; rf < 2; ++rf)
#pragma unroll
    for (int ks = 0; ks < 2; ++ks)
      qf[rf][ks] = ld_bf8_g(qb + bO + (size_t)(qbase + rf * 16 + l15) * 64 + ks * 32 + lh * 8);

  float lsum[2][4];
  f32x4 zero4 = {0.f, 0.f, 0.f, 0.f};
  f32x4 o[2][4];
#pragma unroll
  for (int rf = 0; rf < 2; ++rf) {
#pragma unroll
    for (int r = 0; r < 4; ++r) lsum[rf][r] = 0.f;
#pragma unroll
    for (int dcf = 0; dcf < 4; ++dcf) o[rf][dcf] = zero4;
  }

  char* P = (char*)Pb[wave];
  const unsigned short* kbase = kb + bO + (size_t)l15 * 64 + lh * 8;
  const unsigned short* vbase = vt + bO + (size_t)l15 * 4096 + lh * 8;

#define LOADK(S, KF)                                        \
  {                                                         \
    const unsigned short* kp = kbase + (size_t)(S) * 2048;  \
    KF[0] = ld_bf8_g(kp);                                   \
    KF[1] = ld_bf8_g(kp + 32);                              \
    KF[2] = ld_bf8_g(kp + 1024);                            \
    KF[3] = ld_bf8_g(kp + 1056);                            \
  }

#define COMPUTE(S, KF)                                                         \
  {                                                                            \
    const int s_ = (S);                                                        \
    const unsigned short* vp = vbase + s_ * 32;                                \
    bf16x8 vf0 = ld_bf8_g(vp);                                                 \
    bf16x8 vf1 = ld_bf8_g(vp + 65536);                                         \
    bf16x8 vf2 = ld_bf8_g(vp + 131072);                                        \
    bf16x8 vf3 = ld_bf8_g(vp + 196608);                                        \
    f32x4 sc[2][2];                                                            \
    _Pragma("unroll") for (int rf = 0; rf < 2; ++rf)                           \
        _Pragma("unroll") for (int cf = 0; cf < 2; ++cf) sc[rf][cf] = zero4;   \
    _Pragma("unroll") for (int cf = 0; cf < 2; ++cf)                           \
        _Pragma("unroll") for (int ks = 0; ks < 2; ++ks)                       \
        _Pragma("unroll") for (int rf = 0; rf < 2; ++rf)                       \
            sc[rf][cf] = __builtin_amdgcn_mfma_f32_16x16x32_bf16(              \
                qf[rf][ks], KF[cf * 2 + ks], sc[rf][cf], 0, 0, 0);             \
    if (s_ == t) {                                                             \
      _Pragma("unroll") for (int rf = 0; rf < 2; ++rf)                         \
          _Pragma("unroll") for (int r = 0; r < 4; ++r) {                      \
        int q_ = rf * 16 + lh * 4 + r;                                         \
        _Pragma("unroll") for (int cf = 0; cf < 2; ++cf) {                     \
          int kv = cf * 16 + l15;                                              \
          if (kv > q_) sc[rf][cf][r] = -3.0e38f;                               \
        }                                                                      \
      }                                                                        \
    }                                                                          \
    _Pragma("unroll") for (int rf = 0; rf < 2; ++rf)                           \
        _Pragma("unroll") for (int r = 0; r < 4; ++r) {                        \
      int row = rf * 16 + lh * 4 + r;                                          \
      _Pragma("unroll") for (int cf = 0; cf < 2; ++cf) {                       \
        float p = fast_exp2(sc[rf][cf][r] - SHIFT_L2);                         \
        lsum[rf][r] += p;                                                      \
        *(unsigned short*)(P + ((row * 64 + (cf * 16 + l15) * 2) ^             \
                                ((row & 3) << 4))) = f2bf(p);                  \
      }                                                                        \
    }                                                                          \
    __builtin_amdgcn_wave_barrier();                                           \
    bf16x8 pf[2];                                                              \
    _Pragma("unroll") for (int rf = 0; rf < 2; ++rf) {                         \
      int row = rf * 16 + l15;                                                 \
      pf[rf] = ld_bf8_l(P + ((row * 64 + lh * 16) ^ ((row & 3) << 4)));        \
    }                                                                          \
    _Pragma("unroll") for (int rf = 0; rf < 2; ++rf) {                         \
      o[rf][0] = __builtin_amdgcn_mfma_f32_16x16x32_bf16(pf[rf], vf0, o[rf][0], 0, 0, 0); \
      o[rf][1] = __builtin_amdgcn_mfma_f32_16x16x32_bf16(pf[rf], vf1, o[rf][1], 0, 0, 0); \
      o[rf][2] = __builtin_amdgcn_mfma_f32_16x16x32_bf16(pf[rf], vf2, o[rf][2], 0, 0, 0); \
      o[rf][3] = __builtin_amdgcn_mfma_f32_16x16x32_bf16(pf[rf], vf3, o[rf][3], 0, 0, 0); \
    }                                                                          \
    __builtin_amdgcn_wave_barrier();                                           \
  }

  // ---- 2-phase ping-pong: K for step n+1 prefetched during step n ----
  {
    bf16x8 kA[4], kB[4];
    int s = wave;
    if (s <= t) {
      LOADK(s, kA);
      while (true) {
        int sB = s + 8;
        if (sB <= t) LOADK(sB, kB);
        COMPUTE(s, kA);
        if (sB > t) break;
        int sA = sB + 8;
        if (sA <= t) LOADK(sA, kA);
        COMPUTE(sB, kB);
        if (sA > t) break;
        s = sA;
      }
    }
  }
#undef LOADK
#undef COMPUTE

  // ---- single end-of-sweep l reduce (over the 16 col-lanes) ----
#pragma unroll
  for (int rf = 0; rf < 2; ++rf)
#pragma unroll
    for (int r = 0; r < 4; ++r) {
      float v = lsum[rf][r];
      v += __shfl_xor(v, 1, 64);
      v += __shfl_xor(v, 2, 64);
      v += __shfl_xor(v, 4, 64);
      v += __shfl_xor(v, 8, 64);
      lsum[rf][r] = v;
    }

  // ---- merge 8 per-wave partials: plain sums (no max bookkeeping) ----
  __syncthreads();
#pragma unroll
  for (int rf = 0; rf < 2; ++rf)
#pragma unroll
    for (int r = 0; r < 4; ++r) {
      int row = rf * 16 + lh * 4 + r;
      if (l15 == 0) atomicAdd(&lsumb[row], lsum[rf][r]);
#pragma unroll
      for (int dcf = 0; dcf < 4; ++dcf)
        atomicAdd(&obuf[row * 64 + dcf * 16 + l15], o[rf][dcf][r]);
    }
  __syncthreads();
  {
    int row = tid >> 4, d0 = (tid & 15) * 4;
    float inv = 1.0f / lsumb[row];
    float4v vv = *(float4v*)&obuf[row * 64 + d0];
    vv *= inv;
    *(float4v*)(out + bO + (size_t)(qbase + row) * 64 + d0) = vv;
  }
}

extern "C" void kernel_launch(void* const* d_in, const int* in_sizes, int n_in,
                              void* d_out, int out_size, void* d_ws, size_t ws_size,
                              hipStream_t stream) {
  const float* x  = (const float*)d_in[0];
  const float* wq = (const float*)d_in[1];
  const float* bq = (const float*)d_in[2];
  const float* wk = (const float*)d_in[3];
  const float* bk = (const float*)d_in[4];
  const float* wv = (const float*)d_in[5];
  const float* bv = (const float*)d_in[6];

  unsigned short* Wt   = (unsigned short*)d_ws;     // 192*1024 bf16
  unsigned short* qbuf = Wt + 192 * 1024;           // [b*4096+s][64]
  unsigned short* kbuf = qbuf + 16384 * 64;         // [b*4096+s][64]
  unsigned short* vtb  = kbuf + 16384 * 64;         // [b][64][4096] (V transposed)

  wprep_kernel<<<768, 256, 0, stream>>>(wq, wk, wv, Wt);
  proj_kernel<<<512, 256, 0, stream>>>(x, Wt, bq, bk, bv, qbuf, kbuf, vtb);
  attn_kernel<<<512, 512, 0, stream>>>(qbuf, kbuf, vtb, (float*)d_out);
}

// Round 6
// 92.936 us; speedup vs baseline: 1.2418x; 1.2418x over previous
//
#include <hip/hip_runtime.h>
#include <hip/hip_bf16.h>

using f32x4    = __attribute__((ext_vector_type(4))) float;
using bf16x8   = __attribute__((ext_vector_type(8))) __bf16;
using ushort8  = __attribute__((ext_vector_type(8))) unsigned short;
using ushort4v = __attribute__((ext_vector_type(4))) unsigned short;
using float4v  = __attribute__((ext_vector_type(4))) float;

#define LOG2E 1.44269504088896340736f
#define SHIFT_L2 5.77078016355585f   // 4 * log2(e): p = exp(s_true - 4)

static __device__ __forceinline__ unsigned short f2bf(float f) {
  union { __hip_bfloat16 h; unsigned short u; } cv;
  cv.h = __float2bfloat16(f);
  return cv.u;
}
static __device__ __forceinline__ bf16x8 ld_bf8_g(const unsigned short* p) {
  ushort8 u = *(const ushort8*)p;
  return __builtin_bit_cast(bf16x8, u);
}
static __device__ __forceinline__ bf16x8 ld_bf8_l(const char* p) {
  ushort8 u = *(const ushort8*)p;
  return __builtin_bit_cast(bf16x8, u);
}
static __device__ __forceinline__ float fast_exp2(float x) {
#if __has_builtin(__builtin_amdgcn_exp2f)
  return __builtin_amdgcn_exp2f(x);
#else
  return exp2f(x);
#endif
}
static __device__ __forceinline__ void gload16(const void* g, void* l) {
  __builtin_amdgcn_global_load_lds(
      (const __attribute__((address_space(1))) void*)g,
      (__attribute__((address_space(3))) void*)l, 16, 0, 0);
}

// ---------------- W prep: Wt[col(0..191)][k(0..1023)] bf16 -------------------
__global__ __launch_bounds__(256) void wprep_kernel(
    const float* __restrict__ wq, const float* __restrict__ wk,
    const float* __restrict__ wv, unsigned short* __restrict__ Wt) {
  int idx = blockIdx.x * 256 + threadIdx.x;   // 0 .. 196607
  int col = idx >> 10;                        // 0..191
  int k   = idx & 1023;
  const float* w = (col < 64) ? wq : (col < 128) ? wk : wv;
  int c = col & 63;
  Wt[idx] = f2bf(w[k * 64 + c]);
}

// -------- QKV projection: BM=32 (512 blocks), BN=192, BK=64 -----------------
// q scaled by 1/8*log2(e), layout [b*4096+s][64].
// k,v written into PRE-SWIZZLED 16 KB panels per (batch, 128-row chunk):
//   K panel byte = (r*128 + c*2)  ^ ((r&7)<<4)   (r = s&127, c = 0..63)
//   V panel byte = (d*256 + sl*2) ^ ((d&7)<<4)   (transposed; sl = s&127)
__global__ __launch_bounds__(256) void proj_kernel(
    const float* __restrict__ x, const unsigned short* __restrict__ Wt,
    const float* __restrict__ bq, const float* __restrict__ bk,
    const float* __restrict__ bv,
    unsigned short* __restrict__ qb, unsigned short* __restrict__ kswz,
    unsigned short* __restrict__ vswz) {
  __shared__ __align__(16) char As[32 * 128];   // [32 rows][64 k] bf16, swz (row&7)<<4
  __shared__ __align__(16) char Bs[192 * 128];  // [192 col][64 k] bf16, swz (col&7)<<4
  int tid = threadIdx.x, wave = tid >> 6, lane = tid & 63;
  int rowBase = blockIdx.x * 32;
  int rhalf = (wave & 1) * 16;     // 16-row half
  int chalf = (wave >> 1) * 96;    // 96-col half
  int l15 = lane & 15, lh = lane >> 4;

  f32x4 zero4 = {0.f, 0.f, 0.f, 0.f};
  f32x4 acc[6];
#pragma unroll
  for (int i = 0; i < 6; ++i) acc[i] = zero4;

  for (int kt = 0; kt < 16; ++kt) {
    int k0 = kt * 64;
    {  // stage A: x fp32 -> bf16
      int row = tid >> 3, c0 = (tid & 7) * 8;
      const float4v* src = (const float4v*)(x + (size_t)(rowBase + row) * 1024 + k0 + c0);
      float4v f0 = src[0], f1 = src[1];
      ushort8 u;
#pragma unroll
      for (int e = 0; e < 4; ++e) { u[e] = f2bf(f0[e]); u[4 + e] = f2bf(f1[e]); }
      *(ushort8*)(As + ((row * 128 + c0 * 2) ^ ((row & 7) << 4))) = u;
    }
#pragma unroll
    for (int i = 0; i < 6; ++i) {  // stage B: Wt bf16 [192 col][64 k]
      int c = tid + 256 * i;
      int col = c >> 3, kc = c & 7;
      ushort8 v = *(const ushort8*)(Wt + (size_t)col * 1024 + k0 + kc * 8);
      *(ushort8*)(Bs + ((col * 128 + kc * 16) ^ ((col & 7) << 4))) = v;
    }
    __syncthreads();
    bf16x8 a[2];
#pragma unroll
    for (int ks = 0; ks < 2; ++ks) {
      int row = rhalf + l15;
      a[ks] = ld_bf8_l(As + ((row * 128 + ks * 64 + lh * 16) ^ ((row & 7) << 4)));
    }
#pragma unroll
    for (int cf = 0; cf < 6; ++cf) {
      int col = chalf + cf * 16 + l15;
#pragma unroll
      for (int ks = 0; ks < 2; ++ks) {
        bf16x8 b = ld_bf8_l(Bs + ((col * 128 + ks * 64 + lh * 16) ^ ((col & 7) << 4)));
        acc[cf] = __builtin_amdgcn_mfma_f32_16x16x32_bf16(a[ks], b, acc[cf], 0, 0, 0);
      }
    }
    __syncthreads();
  }
#pragma unroll
  for (int cf = 0; cf < 6; ++cf) {
    int col = chalf + cf * 16 + l15;
    int sel = col >> 6, c64 = col & 63;
    const float* bias = (sel == 0) ? bq : (sel == 1) ? bk : bv;
    float bb = bias[c64];
    if (sel == 0) {
#pragma unroll
      for (int r = 0; r < 4; ++r) {
        int row = rowBase + rhalf + lh * 4 + r;
        qb[(size_t)row * 64 + c64] = f2bf((acc[cf][r] + bb) * (0.125f * LOG2E));
      }
    } else if (sel == 1) {
#pragma unroll
      for (int r = 0; r < 4; ++r) {
        int s = rowBase + rhalf + lh * 4 + r;
        int b = s >> 12, sl = s & 4095;
        int ch = sl >> 7, rl = sl & 127;
        int byte = (rl * 128 + c64 * 2) ^ ((rl & 7) << 4);
        *(unsigned short*)((char*)kswz + (((size_t)(b * 32 + ch)) << 14) + byte) =
            f2bf(acc[cf][r] + bb);
      }
    } else {
      ushort4v w;
#pragma unroll
      for (int r = 0; r < 4; ++r) w[r] = f2bf(acc[cf][r] + bb);
      int s0 = rowBase + rhalf + lh * 4;
      int b = s0 >> 12, sl0 = s0 & 4095;
      int ch = sl0 >> 7, r0 = sl0 & 127;
      int byte = (c64 * 256 + r0 * 2) ^ ((c64 & 7) << 4);
      *(ushort4v*)((char*)vswz + (((size_t)(b * 32 + ch)) << 14) + byte) = w;
    }
  }
}

// ---- causal flash attention: LDS-shared KV, double-buffer, counted vmcnt ----
// grid 256 = 4 batch x 64 q-tiles(64 rows); 1024 thr = 16 waves (4 q x 4 kv).
__global__ __launch_bounds__(1024, 4) void attn_kernel(
    const unsigned short* __restrict__ qb, const unsigned short* __restrict__ kswz,
    const unsigned short* __restrict__ vswz, float* __restrict__ out) {
  extern __shared__ __align__(16) char smem[];
  char* Kb0 = smem;                      // 16 KB  K panel buf0
  char* Kb1 = smem + 16384;              // 16 KB  buf1
  char* Vb0 = smem + 32768;              // 16 KB  V panel buf0
  char* Vb1 = smem + 49152;              // 16 KB  buf1
  char* Pall = smem + 65536;             // 16 x 1 KB per-wave P
  float* obuf = (float*)(smem + 81920);  // [64][64] f32 merge
  float* lsumb = (float*)(smem + 98304); // [64]

  int tid = threadIdx.x, wave = tid >> 6, lane = tid & 63;
  int l15 = lane & 15, lh = lane >> 4;
  int bid = blockIdx.x;
  int batch = bid & 3;
  int T = bid >> 2;                 // q tile 0..63
  int Tq = T * 64;
  int nch = (T + 2) >> 1;           // ceil((T+1)/2) KV chunks of 128
  int qq = wave >> 2;               // q quarter (16 rows)
  int kvq = wave & 3;               // kv quarter (32 kv)
  const size_t bO = (size_t)batch * 262144;

  // init merge buffers
  *(float4v*)(obuf + tid * 4) = (float4v){0.f, 0.f, 0.f, 0.f};
  if (tid < 64) lsumb[tid] = 0.f;
  __syncthreads();

  bf16x8 qf[2];
#pragma unroll
  for (int ks = 0; ks < 2; ++ks)
    qf[ks] = ld_bf8_g(qb + bO + (size_t)(Tq + qq * 16 + l15) * 64 + ks * 32 + lh * 8);

  f32x4 zero4 = {0.f, 0.f, 0.f, 0.f};
  f32x4 o[4];
  float lsum[4];
#pragma unroll
  for (int i = 0; i < 4; ++i) { o[i] = zero4; lsum[i] = 0.f; }

  const char* kpan = (const char*)kswz + ((size_t)batch << 19);  // 32 x 16 KB
  const char* vpan = (const char*)vswz + ((size_t)batch << 19);
  int woff = wave * 1024;               // this wave's 1 KB slice of a panel
  char* P = Pall + wave * 1024;

#define STAGE(C, KD, VD)                                         \
  {                                                              \
    size_t po = ((size_t)(C) << 14) + woff + lane * 16;          \
    gload16(kpan + po, (KD) + woff);                             \
    gload16(vpan + po, (VD) + woff);                             \
  }

  STAGE(0, Kb0, Vb0)

  for (int c = 0; c < nch; ++c) {
    char* Kc = (c & 1) ? Kb1 : Kb0;
    char* Vc = (c & 1) ? Vb1 : Vb0;
    char* Kn = (c & 1) ? Kb0 : Kb1;
    char* Vn = (c & 1) ? Vb0 : Vb1;
    asm volatile("" ::: "memory");
    __builtin_amdgcn_s_barrier();         // A: everyone done with buf being overwritten
    if (c + 1 < nch) {
      STAGE(c + 1, Kn, Vn)
      asm volatile("s_waitcnt vmcnt(2)" ::: "memory");  // chunk c's loads done
    } else {
      asm volatile("s_waitcnt vmcnt(0)" ::: "memory");
    }
    __builtin_amdgcn_s_barrier();         // B: chunk c visible to all waves
    __builtin_amdgcn_sched_barrier(0);

    // ---- QK^T: 16q x 32kv ----
    f32x4 sc[2];
    sc[0] = zero4; sc[1] = zero4;
#pragma unroll
    for (int cf = 0; cf < 2; ++cf) {
      int kr = kvq * 32 + cf * 16 + l15;
#pragma unroll
      for (int ks = 0; ks < 2; ++ks) {
        bf16x8 kf = ld_bf8_l(Kc + ((kr * 128 + ks * 64 + lh * 16) ^ ((kr & 7) << 4)));
        sc[cf] = __builtin_amdgcn_mfma_f32_16x16x32_bf16(qf[ks], kf, sc[cf], 0, 0, 0);
      }
    }
    if (c * 128 + 127 > Tq) {  // causal mask needed in this chunk
#pragma unroll
      for (int r = 0; r < 4; ++r) {
        int qg = Tq + qq * 16 + lh * 4 + r;
#pragma unroll
        for (int cf = 0; cf < 2; ++cf) {
          int kvg = c * 128 + kvq * 32 + cf * 16 + l15;
          if (kvg > qg) sc[cf][r] = -3.0e38f;
        }
      }
    }
    // ---- p = exp2(s - SHIFT), stage P, PV ----
#pragma unroll
    for (int r = 0; r < 4; ++r) {
      int row = lh * 4 + r;
#pragma unroll
      for (int cf = 0; cf < 2; ++cf) {
        float p = fast_exp2(sc[cf][r] - SHIFT_L2);
        lsum[r] += p;
        *(unsigned short*)(P + row * 64 + (cf * 16 + l15) * 2) = f2bf(p);
      }
    }
    __builtin_amdgcn_wave_barrier();
    bf16x8 pf = ld_bf8_l(P + l15 * 64 + lh * 16);
#pragma unroll
    for (int dcf = 0; dcf < 4; ++dcf) {
      int d = dcf * 16 + l15;
      bf16x8 vf = ld_bf8_l(Vc + ((d * 256 + kvq * 64 + lh * 16) ^ ((d & 7) << 4)));
      o[dcf] = __builtin_amdgcn_mfma_f32_16x16x32_bf16(pf, vf, o[dcf], 0, 0, 0);
    }
    __builtin_amdgcn_wave_barrier();
  }
#undef STAGE

  // ---- merge 16 per-wave partials (4 kv-waves per q-quarter) ----
#pragma unroll
  for (int r = 0; r < 4; ++r) {
    float v = lsum[r];
    v += __shfl_xor(v, 1, 64);
    v += __shfl_xor(v, 2, 64);
    v += __shfl_xor(v, 4, 64);
    v += __shfl_xor(v, 8, 64);
    int row = qq * 16 + lh * 4 + r;
    if (l15 == 0) atomicAdd(&lsumb[row], v);
#pragma unroll
    for (int dcf = 0; dcf < 4; ++dcf)
      atomicAdd(&obuf[row * 64 + dcf * 16 + l15], o[dcf][r]);
  }
  __syncthreads();
  {
    int row = tid >> 4, d0 = (tid & 15) * 4;
    float inv = 1.0f / lsumb[row];
    float4v vv = *(float4v*)&obuf[row * 64 + d0];
    vv *= inv;
    *(float4v*)(out + bO + (size_t)(Tq + row) * 64 + d0) = vv;
  }
}

extern "C" void kernel_launch(void* const* d_in, const int* in_sizes, int n_in,
                              void* d_out, int out_size, void* d_ws, size_t ws_size,
                              hipStream_t stream) {
  const float* x  = (const float*)d_in[0];
  const float* wq = (const float*)d_in[1];
  const float* bq = (const float*)d_in[2];
  const float* wk = (const float*)d_in[3];
  const float* bk = (const float*)d_in[4];
  const float* wv = (const float*)d_in[5];
  const float* bv = (const float*)d_in[6];

  unsigned short* Wt   = (unsigned short*)d_ws;     // 192*1024
  unsigned short* qbuf = Wt + 192 * 1024;           // [b*4096+s][64]
  unsigned short* kswz = qbuf + 16384 * 64;         // 4 x 32 x 8192 (swizzled panels)
  unsigned short* vswz = kswz + 16384 * 64;         // 4 x 32 x 8192

  wprep_kernel<<<768, 256, 0, stream>>>(wq, wk, wv, Wt);
  proj_kernel<<<512, 256, 0, stream>>>(x, Wt, bq, bk, bv, qbuf, kswz, vswz);
  attn_kernel<<<256, 1024, 98560, stream>>>(qbuf, kswz, vswz, (float*)d_out);
}